// Round 9
// baseline (237.640 us; speedup 1.0000x reference)
//
#include <hip/hip_runtime.h>
#include <hip/hip_bf16.h>
#include <math.h>

#define DIM 384
#define HEADS 6
#define HIDDEN 1536
#define NTOK 2744   // 14*14*14
#define NTOKP 2752  // 43*64, padded key stride for VT
#define BATCH 2
#define MTOT (BATCH * NTOK)   // 5488
#define KSPLIT 4
#define NQB 22      // ceil(2744/128)  (128 queries per attn block)
#define CEXP 0.18033688f   // (1/8) * log2(e)

typedef __bf16 bf16x8 __attribute__((ext_vector_type(8)));
typedef __bf16 bf16x4 __attribute__((ext_vector_type(4)));
typedef float  f32x4  __attribute__((ext_vector_type(4)));

#define F_GELU  1
#define F_RESID 2
#define F_BF16  4
#define F_QKV   8
#define F_TRANS 16

// async global->LDS, 16B per lane; LDS dest = uniform base + lane*16
__device__ __forceinline__ void gll16(const void* g, void* l) {
    __builtin_amdgcn_global_load_lds(
        (const __attribute__((address_space(1))) unsigned int*)g,
        (__attribute__((address_space(3))) unsigned int*)l, 16, 0, 0);
}

// ---------------------------------------------------------------------------
// k_conv: depthwise conv3d (+residual) with WRITE-COMBINED output.
// Tail blocks: weight fp32->bf16 conversion (1728) + VT pad zeroing (1).
// ---------------------------------------------------------------------------
__global__ void k_conv(const float* __restrict__ x, const float* __restrict__ cw,
                       float* __restrict__ t,
                       const float* __restrict__ w0, const float* __restrict__ w1,
                       const float* __restrict__ w2, const float* __restrict__ w3,
                       __bf16* o0, __bf16* o1, __bf16* o2, __bf16* o3,
                       __bf16* vt_pad) {
    int bid = blockIdx.x;
    if (bid >= 2256) {   // ---- VT pad zeroing: slots p=11,15 of tile 42 ----
        #pragma unroll
        for (int k = 0; k < 6; k++) {
            int idx = k * 256 + threadIdx.x;   // 0..1535
            int row = idx >> 1, half = idx & 1;
            bf16x4 z4 = { (__bf16)0.f, (__bf16)0.f, (__bf16)0.f, (__bf16)0.f };
            *(bf16x4*)(vt_pad + (size_t)row * NTOKP + 2732 + half * 16) = z4;
        }
        return;
    }
    if (bid >= 528) {   // ---- weight conversion ----
        int i = (bid - 528) * 256 + threadIdx.x;   // float4 index
        const float* s; __bf16* d; int off;
        if (i < 110592)      { s = w0; d = o0; off = i; }
        else if (i < 147456) { s = w1; d = o1; off = i - 110592; }
        else if (i < 294912) { s = w2; d = o2; off = i - 147456; }
        else                 { s = w3; d = o3; off = i - 294912; }
        float4 v = ((const float4*)s)[off];
        bf16x4 bb = { (__bf16)v.x, (__bf16)v.y, (__bf16)v.z, (__bf16)v.w };
        *(bf16x4*)(d + (size_t)off * 4) = bb;
        return;
    }
    int nb = bid % 11, rest = bid / 11;
    int cb = rest % 24, b = rest / 24;
    int c0 = cb * 16;
    int n = nb * 256 + threadIdx.x;
    if (n >= NTOK) return;
    int d = n / 196, r = n % 196, h = r / 14, w = r % 14;
    const float* xb = x + ((size_t)b * DIM + c0) * NTOK;
    float acc[16];
    #pragma unroll
    for (int c = 0; c < 16; c++) acc[c] = xb[(size_t)c * NTOK + n];   // residual
    #pragma unroll
    for (int kd = 0; kd < 3; kd++) {
        int dd = d + kd - 1;
        if (dd < 0 || dd >= 14) continue;
        #pragma unroll
        for (int kh = 0; kh < 3; kh++) {
            int hh = h + kh - 1;
            if (hh < 0 || hh >= 14) continue;
            #pragma unroll
            for (int kw = 0; kw < 3; kw++) {
                int ww = w + kw - 1;
                if (ww < 0 || ww >= 14) continue;
                int np = (dd * 14 + hh) * 14 + ww;
                int tap = kd * 9 + kh * 3 + kw;
                #pragma unroll
                for (int c = 0; c < 16; c++)   // weight idx block-uniform -> s_load
                    acc[c] = fmaf(cw[(c0 + c) * 27 + tap], xb[(size_t)c * NTOK + np], acc[c]);
            }
        }
    }
    float* tp = t + (size_t)(b * NTOK + n) * DIM + c0;   // 64 B aligned line
    #pragma unroll
    for (int c = 0; c < 16; c += 4) {
        float4 v = { acc[c], acc[c + 1], acc[c + 2], acc[c + 3] };
        *(float4*)(tp + c) = v;
    }
}

// ---------------------------------------------------------------------------
// k_ln1 / k_ln2: LayerNorm fp32 in -> bf16 out. One wave per token.
// ---------------------------------------------------------------------------
__device__ __forceinline__ void ln_body(const float* __restrict__ in,
                                        __bf16* __restrict__ out,
                                        const float* __restrict__ w,
                                        const float* __restrict__ b) {
    int wid = threadIdx.x >> 6, lane = threadIdx.x & 63;
    int token = blockIdx.x * 4 + wid;
    const float* row = in + (size_t)token * DIM;
    float v[6], s = 0.f, s2 = 0.f;
    #pragma unroll
    for (int i = 0; i < 6; i++) {
        v[i] = row[lane + 64 * i];
        s += v[i]; s2 += v[i] * v[i];
    }
    #pragma unroll
    for (int m = 1; m < 64; m <<= 1) { s += __shfl_xor(s, m); s2 += __shfl_xor(s2, m); }
    float mu = s * (1.f / DIM);
    float rstd = rsqrtf(s2 * (1.f / DIM) - mu * mu + 1e-5f);
    __bf16* orow = out + (size_t)token * DIM;
    #pragma unroll
    for (int i = 0; i < 6; i++) {
        int c = lane + 64 * i;
        orow[c] = (__bf16)((v[i] - mu) * rstd * w[c] + b[c]);
    }
}
__global__ void k_ln1(const float* in, __bf16* out, const float* w, const float* b) {
    ln_body(in, out, w, b);
}
__global__ void k_ln2(const float* in, __bf16* out, const float* w, const float* b) {
    ln_body(in, out, w, b);
}

// ---------------------------------------------------------------------------
// gemm 128x128x64 (m93 pattern: 4x4 acc/wave -> 2x MFMA per staged byte and
// per barrier vs 128x64), SINGLE-buffered 32 KB LDS, XOR chunk swizzle.
// QKV / FC1. V output goes to VT2 (padded stride, t/q-swapped tiles).
// ---------------------------------------------------------------------------
__device__ __forceinline__ void gemm128128_body(
    const __bf16* __restrict__ A, const __bf16* __restrict__ B,
    const float* __restrict__ bias, void* __restrict__ out,
    __bf16* __restrict__ vt_out, int M, int N, int K, int flags) {
    __shared__ __bf16 As[128][64];   // 16 KB
    __shared__ __bf16 Bs[128][64];   // 16 KB
    int tid = threadIdx.x, lane = tid & 63, wid = tid >> 6;
    int quad = lane >> 4, l16 = lane & 15;
    int wm = wid & 1, wn = wid >> 1;
    int m0 = blockIdx.y * 128, n0 = blockIdx.x * 128;
    int x7 = l16 & 7;

    auto stage = [&](int k0) {
        #pragma unroll
        for (int i = 0; i < 4; i++) {
            int c = i * 256 + tid;
            int row = c >> 3, cc = (c & 7) ^ (row & 7);
            int gm = m0 + row; if (gm > M - 1) gm = M - 1;
            gll16(A + (size_t)gm * K + k0 + cc * 8, &As[0][0] + (size_t)c * 8);
        }
        #pragma unroll
        for (int i = 0; i < 4; i++) {
            int c = i * 256 + tid;
            int row = c >> 3, cc = (c & 7) ^ (row & 7);
            gll16(B + (size_t)(n0 + row) * K + k0 + cc * 8, &Bs[0][0] + (size_t)c * 8);
        }
    };

    f32x4 acc[4][4] = {};
    int nk = K >> 6;
    for (int ki = 0; ki < nk; ki++) {
        if (ki) __syncthreads();
        stage(ki << 6);
        __syncthreads();
        #pragma unroll
        for (int s = 0; s < 2; s++) {
            bf16x8 a[4], b[4];
            #pragma unroll
            for (int i = 0; i < 4; i++)
                a[i] = *(bf16x8*)&As[wm * 64 + i * 16 + l16][(((s * 4 + quad) ^ x7)) * 8];
            #pragma unroll
            for (int j = 0; j < 4; j++)
                b[j] = *(bf16x8*)&Bs[wn * 64 + j * 16 + l16][(((s * 4 + quad) ^ x7)) * 8];
            #pragma unroll
            for (int i = 0; i < 4; i++)
                #pragma unroll
                for (int j = 0; j < 4; j++)
                    acc[i][j] = __builtin_amdgcn_mfma_f32_16x16x32_bf16(a[i], b[j], acc[i][j], 0, 0, 0);
        }
    }

    int colb = n0 + wn * 64;
    #pragma unroll
    for (int j = 0; j < 4; j++) {
        int col = colb + j * 16 + l16;
        float bv = bias ? bias[col] : 0.f;
        #pragma unroll
        for (int i = 0; i < 4; i++) {
            int row0 = m0 + wm * 64 + i * 16 + quad * 4;
            if (row0 >= M) continue;
            float v4[4];
            #pragma unroll
            for (int r = 0; r < 4; r++) {
                float v = acc[i][j][r] + bv;
                if (flags & F_GELU) v = 0.5f * v * (1.f + erff(v * 0.70710678f));
                if ((flags & F_QKV) && col < 384) v *= CEXP;   // pre-scale Q
                v4[r] = v;
            }
            if ((flags & F_QKV) && col >= 768) {
                int b2 = row0 / NTOK, n2 = row0 - b2 * NTOK;
                // t/q-swap within 64-key tile: k' = q*16 + t*4 + r
                int n2p = (n2 & ~63) | (((n2 >> 2) & 3) << 4) | (((n2 >> 4) & 3) << 2);
                bf16x4 pk = { (__bf16)v4[0], (__bf16)v4[1], (__bf16)v4[2], (__bf16)v4[3] };
                *(bf16x4*)(vt_out + ((size_t)(b2 * DIM + (col - 768))) * NTOKP + n2p) = pk;
            } else {
                #pragma unroll
                for (int r = 0; r < 4; r++)
                    ((__bf16*)out)[(size_t)(row0 + r) * N + col] = (__bf16)v4[r];
            }
        }
    }
}
__global__ __launch_bounds__(256) void k_qkv(const __bf16* A, const __bf16* B,
        void* out, __bf16* vt_out, int M, int N, int K) {
    gemm128128_body(A, B, nullptr, out, vt_out, M, N, K, F_QKV);
}
__global__ __launch_bounds__(256) void k_fc1(const __bf16* A, const __bf16* B,
        const float* bias, void* out, int M, int N, int K) {
    gemm128128_body(A, B, bias, out, nullptr, M, N, K, F_GELU | F_BF16);
}

// ---------------------------------------------------------------------------
// gemm 128x64x64, SINGLE-buffered (24 KB LDS), XOR chunk swizzle. PROJ.
// F_RESID: float out += resid.
// ---------------------------------------------------------------------------
__device__ __forceinline__ void gemm12864_body(
    const __bf16* __restrict__ A, const __bf16* __restrict__ B,
    const float* __restrict__ bias, const float* __restrict__ resid,
    void* __restrict__ out, int M, int N, int K, int flags) {
    __shared__ __bf16 As[128][64];   // 16 KB
    __shared__ __bf16 Bs[64][64];    //  8 KB
    int tid = threadIdx.x, lane = tid & 63, wid = tid >> 6;
    int quad = lane >> 4, l16 = lane & 15;
    int wm = wid & 1, wn = wid >> 1;
    int m0 = blockIdx.y * 128, n0 = blockIdx.x * 64;
    int x7 = l16 & 7;

    auto stage = [&](int k0) {
        #pragma unroll
        for (int i = 0; i < 4; i++) {
            int c = i * 256 + tid;
            int row = c >> 3, cc = (c & 7) ^ (row & 7);
            int gm = m0 + row; if (gm > M - 1) gm = M - 1;
            gll16(A + (size_t)gm * K + k0 + cc * 8, &As[0][0] + (size_t)c * 8);
        }
        #pragma unroll
        for (int i = 0; i < 2; i++) {
            int c = i * 256 + tid;
            int row = c >> 3, cc = (c & 7) ^ (row & 7);
            gll16(B + (size_t)(n0 + row) * K + k0 + cc * 8, &Bs[0][0] + (size_t)c * 8);
        }
    };

    f32x4 acc[4][2] = {};
    int nk = K >> 6;
    for (int ki = 0; ki < nk; ki++) {
        if (ki) __syncthreads();
        stage(ki << 6);
        __syncthreads();
        #pragma unroll
        for (int s = 0; s < 2; s++) {
            bf16x8 a[4], b[2];
            #pragma unroll
            for (int i = 0; i < 4; i++)
                a[i] = *(bf16x8*)&As[wm * 64 + i * 16 + l16][(((s * 4 + quad) ^ x7)) * 8];
            #pragma unroll
            for (int j = 0; j < 2; j++)
                b[j] = *(bf16x8*)&Bs[wn * 32 + j * 16 + l16][(((s * 4 + quad) ^ x7)) * 8];
            #pragma unroll
            for (int i = 0; i < 4; i++)
                #pragma unroll
                for (int j = 0; j < 2; j++)
                    acc[i][j] = __builtin_amdgcn_mfma_f32_16x16x32_bf16(a[i], b[j], acc[i][j], 0, 0, 0);
        }
    }

    int colb = n0 + wn * 32;
    #pragma unroll
    for (int j = 0; j < 2; j++) {
        int col = colb + j * 16 + l16;
        float bv = bias ? bias[col] : 0.f;
        #pragma unroll
        for (int i = 0; i < 4; i++) {
            int row0 = m0 + wm * 64 + i * 16 + quad * 4;
            if (row0 >= M) continue;
            #pragma unroll
            for (int r = 0; r < 4; r++) {
                float v = acc[i][j][r] + bv;
                if (flags & F_RESID) v += resid[(size_t)(row0 + r) * N + col];
                ((float*)out)[(size_t)(row0 + r) * N + col] = v;
            }
        }
    }
}
__global__ __launch_bounds__(256) void k_proj(const __bf16* A, const __bf16* B,
        const float* bias, const float* resid, void* out, int M, int N, int K) {
    gemm12864_body(A, B, bias, resid, out, M, N, K, F_RESID);
}

// ---------------------------------------------------------------------------
// gemm 64x64x64, SINGLE-buffered, fc2 only. F_TRANS path does an LDS
// transpose (two 32-col halves, [32][68] fp32) so the out[b,c,n] store is
// 256 B-contiguous coalesced.
// ---------------------------------------------------------------------------
__device__ __forceinline__ void gemm64_body(
    const __bf16* __restrict__ A, const __bf16* __restrict__ B,
    const float* __restrict__ bias, const float* __restrict__ resid,
    void* __restrict__ out, int M, int N, int K, int flags) {
    __shared__ __align__(16) char sm[17408];   // As 8K @0, Bs 8K @8192; Tt reuse
    __bf16 (*As)[64] = (__bf16(*)[64])sm;
    __bf16 (*Bs)[64] = (__bf16(*)[64])(sm + 8192);
    float* Tt = (float*)sm;                    // [32][68] fp32 = 8704 B
    int tid = threadIdx.x, lane = tid & 63, wid = tid >> 6;
    int quad = lane >> 4, l16 = lane & 15;
    int wm = wid & 1, wn = wid >> 1;
    int m0 = blockIdx.y * 64, n0 = blockIdx.x * 64;
    int x7 = l16 & 7;

    auto stage = [&](int k0) {
        #pragma unroll
        for (int i = 0; i < 2; i++) {
            int c = i * 256 + tid;
            int row = c >> 3, cc = (c & 7) ^ (row & 7);
            int gm = m0 + row; if (gm > M - 1) gm = M - 1;
            gll16(A + (size_t)gm * K + k0 + cc * 8, &As[0][0] + (size_t)c * 8);
        }
        #pragma unroll
        for (int i = 0; i < 2; i++) {
            int c = i * 256 + tid;
            int row = c >> 3, cc = (c & 7) ^ (row & 7);
            gll16(B + (size_t)(n0 + row) * K + k0 + cc * 8, &Bs[0][0] + (size_t)c * 8);
        }
    };

    f32x4 acc[2][2] = {};
    int nk = K >> 6;
    for (int ki = 0; ki < nk; ki++) {
        if (ki) __syncthreads();
        stage(ki << 6);
        __syncthreads();
        #pragma unroll
        for (int s = 0; s < 2; s++) {
            bf16x8 a[2], b[2];
            #pragma unroll
            for (int i = 0; i < 2; i++)
                a[i] = *(bf16x8*)&As[wm * 32 + i * 16 + l16][(((s * 4 + quad) ^ x7)) * 8];
            #pragma unroll
            for (int j = 0; j < 2; j++)
                b[j] = *(bf16x8*)&Bs[wn * 32 + j * 16 + l16][(((s * 4 + quad) ^ x7)) * 8];
            #pragma unroll
            for (int i = 0; i < 2; i++)
                #pragma unroll
                for (int j = 0; j < 2; j++)
                    acc[i][j] = __builtin_amdgcn_mfma_f32_16x16x32_bf16(a[i], b[j], acc[i][j], 0, 0, 0);
        }
    }

    if (flags & F_TRANS) {
        // coalesced transposed store via LDS, two 32-col halves
        #pragma unroll
        for (int half = 0; half < 2; half++) {
            __syncthreads();   // staging (or prior half) reads done
            if (wn == half) {
                #pragma unroll
                for (int j = 0; j < 2; j++) {
                    int colL = j * 16 + l16;                 // 0..31 in half
                    int col = n0 + half * 32 + colL;
                    float bv = bias[col];
                    #pragma unroll
                    for (int i = 0; i < 2; i++) {
                        int rowL = wm * 32 + i * 16 + quad * 4;
                        float v4[4];
                        #pragma unroll
                        for (int r = 0; r < 4; r++) {
                            int rr = m0 + rowL + r; if (rr > M - 1) rr = M - 1;
                            v4[r] = acc[i][j][r] + bv + resid[(size_t)rr * N + col];
                        }
                        float4 pk = { v4[0], v4[1], v4[2], v4[3] };
                        *(float4*)&Tt[colL * 68 + rowL] = pk;
                    }
                }
            }
            __syncthreads();
            int c = tid >> 3, no = (tid & 7) * 8;
            int col = n0 + half * 32 + c;
            #pragma unroll
            for (int q2 = 0; q2 < 2; q2++) {
                int nn = no + q2 * 4;
                int row = m0 + nn;
                if (row >= M) continue;
                int b2 = row / NTOK, n2 = row - b2 * NTOK;
                float4 v = *(float4*)&Tt[c * 68 + nn];
                *(float4*)((float*)out + ((size_t)(b2 * N + col)) * NTOK + n2) = v;
            }
        }
        return;
    }

    #pragma unroll
    for (int j = 0; j < 2; j++) {
        int col = n0 + wn * 32 + j * 16 + l16;
        float bv = bias ? bias[col] : 0.f;
        #pragma unroll
        for (int i = 0; i < 2; i++) {
            int row0 = m0 + wm * 32 + i * 16 + quad * 4;
            if (row0 >= M) continue;
            #pragma unroll
            for (int r = 0; r < 4; r++) {
                float v = acc[i][j][r] + bv;
                if (flags & F_RESID) v += resid[(size_t)(row0 + r) * N + col];
                ((float*)out)[(size_t)(row0 + r) * N + col] = v;
            }
        }
    }
}
__global__ __launch_bounds__(256) void k_fc2(const __bf16* A, const __bf16* B,
        const float* bias, const float* resid, void* out, int M, int N, int K) {
    gemm64_body(A, B, bias, resid, out, M, N, K, F_RESID | F_TRANS);
}

// ---------------------------------------------------------------------------
// k_attn (best measured 48.6us): zero-LDS softmax, 8 waves x 16 q,
// KSPLIT=4, grid 1056 (4.1 blocks/CU), VT2 b128 PV, wave-linear OP stores,
// XCD grouping. setprio kept (null but harmless).
// ---------------------------------------------------------------------------
__global__ __launch_bounds__(512, 8) void k_attn(const __bf16* __restrict__ qkv,
                                                 const __bf16* __restrict__ vt,
                                                 __bf16* __restrict__ opart,
                                                 float* __restrict__ lpart) {
    __shared__ __align__(16) __bf16 KV[2][2][64][64];   // 32 KB: [buf][K/V][row][col]
    __bf16 (*Qs)[64] = (__bf16(*)[64])KV;               // 16 KB overlay (= buf0)

    int tid = threadIdx.x, lane = tid & 63, wid = tid >> 6;
    int quad = lane >> 4, l16 = lane & 15;
    // XCD-aware remap: flat%8 = XCD (round-robin dispatch); same (bh,ks) -> one XCD
    int flat = blockIdx.x;
    int xcd = flat & 7, slot = flat >> 3;     // slot 0..131
    int grp = slot / NQB, qb = slot - grp * NQB;
    int g = xcd + 8 * grp;                    // 0..47
    int bh = g % 12, ks = g / 12;
    int q0 = qb * 128;
    int b = bh / HEADS, h = bh % HEADS;
    int x7 = l16 & 7;

    int kt0 = (43 * ks) / KSPLIT, kt1 = (43 * (ks + 1)) / KSPLIT;

    // per-thread staging geometry: one gll16 each for K and V per tile
    int srow = tid >> 3, scc = (tid & 7) ^ (srow & 7);
    const __bf16* pK = qkv + ((size_t)(b * NTOK + kt0 * 64 + srow)) * 1152 + 384 + h * 64 + scc * 8;
    const __bf16* pV = vt + ((size_t)(bh * 64 + srow)) * NTOKP + kt0 * 64 + scc * 8;

    auto stageKV = [&](int kt, int bufi) {
        const __bf16* kp = pK + (size_t)(kt - kt0) * (64 * 1152);
        if (kt == 42 && srow >= 56)   // clamp tail rows (keys >= NTOK)
            kp = qkv + ((size_t)(b * NTOK + NTOK - 1)) * 1152 + 384 + h * 64 + scc * 8;
        gll16(kp, &KV[bufi][0][0][0] + (size_t)tid * 8);
        gll16(pV + (size_t)(kt - kt0) * 64, &KV[bufi][1][0][0] + (size_t)tid * 8);
    };

    // ---- prologue: stage Q (128 rows = 1024 granules) into the buf0 overlay ----
    #pragma unroll
    for (int i = 0; i < 2; i++) {
        int c = i * 512 + tid;
        int row = c >> 3, cc = (c & 7) ^ (row & 7);
        int gq = q0 + row; if (gq > NTOK - 1) gq = NTOK - 1;
        gll16(qkv + ((size_t)(b * NTOK + gq)) * 1152 + h * 64 + cc * 8,
              &Qs[0][0] + (size_t)c * 8);
    }
    __syncthreads();   // Q staged

    bf16x8 aq[2];
    #pragma unroll
    for (int sx = 0; sx < 2; sx++)
        aq[sx] = *(bf16x8*)&Qs[wid * 16 + l16][((sx * 4 + quad) ^ x7) * 8];
    __syncthreads();   // all waves done reading Qs before buf0 overwrite

    stageKV(kt0, 0);

    // lane-constant LDS read offsets (elements)
    int koff0 = (quad ^ x7) * 8, koff1 = ((4 + quad) ^ x7) * 8;
    int voff0 = ((quad * 2 + 0) ^ x7) * 8, voff1 = ((quad * 2 + 1) ^ x7) * 8;

    const f32x4 fzero = {0.f, 0.f, 0.f, 0.f};
    f32x4 oaccT[4] = {};   // O^T: row d = dt*16+quad*4+r, col q = l16
    float l_sum = 0.f;

    int bufi = 0;
    for (int kt = kt0; kt < kt1; kt++) {
        __syncthreads();                          // stage(kt) landed; prev readers done
        if (kt + 1 < kt1) stageKV(kt + 1, bufi ^ 1);   // prefetch next tile

        const __bf16* ksb = &KV[bufi][0][0][0] + l16 * 64;
        const __bf16* vtb = &KV[bufi][1][0][0] + l16 * 64;
        bool tail = (kt == 42);

        // S^T per 16-key block t; exp in-register -> pb B-fragments (no LDS)
        bf16x8 pb[2];
        #pragma unroll
        for (int t = 0; t < 4; t++) {
            bf16x8 bk0 = *(bf16x8*)(ksb + t * 1024 + koff0);
            bf16x8 bk1 = *(bf16x8*)(ksb + t * 1024 + koff1);
            __builtin_amdgcn_s_setprio(1);
            f32x4 z = __builtin_amdgcn_mfma_f32_16x16x32_bf16(bk0, aq[0], fzero, 0, 0, 0);
            z = __builtin_amdgcn_mfma_f32_16x16x32_bf16(bk1, aq[1], z, 0, 0, 0);
            __builtin_amdgcn_s_setprio(0);
            float e0 = exp2f(z[0]), e1 = exp2f(z[1]), e2 = exp2f(z[2]), e3 = exp2f(z[3]);
            if (tail) {
                int kb = kt * 64 + t * 16 + quad * 4;
                if (kb + 0 >= NTOK) e0 = 0.f;
                if (kb + 1 >= NTOK) e1 = 0.f;
                if (kb + 2 >= NTOK) e2 = 0.f;
                if (kb + 3 >= NTOK) e3 = 0.f;
            }
            l_sum += (e0 + e1) + (e2 + e3);
            int half = (t & 1) * 4, px = t >> 1;
            pb[px][half + 0] = (__bf16)e0;
            pb[px][half + 1] = (__bf16)e1;
            pb[px][half + 2] = (__bf16)e2;
            pb[px][half + 3] = (__bf16)e3;
        }

        // PV: per (dt,sx) ONE contiguous b128 V^T fragment (VT2 layout), 2 MFMA
        __builtin_amdgcn_s_setprio(1);
        #pragma unroll
        for (int dt = 0; dt < 4; dt++) {
            const __bf16* vr = vtb + dt * 1024;
            bf16x8 av0 = *(bf16x8*)(vr + voff0);
            bf16x8 av1 = *(bf16x8*)(vr + voff1);
            oaccT[dt] = __builtin_amdgcn_mfma_f32_16x16x32_bf16(av0, pb[0], oaccT[dt], 0, 0, 0);
            oaccT[dt] = __builtin_amdgcn_mfma_f32_16x16x32_bf16(av1, pb[1], oaccT[dt], 0, 0, 0);
        }
        __builtin_amdgcn_s_setprio(0);
        bufi ^= 1;
    }

    // softmax denominator: per-lane partials, reduce across quads (2 shuffles)
    float l = l_sum;
    l += __shfl_xor(l, 16);
    l += __shfl_xor(l, 32);
    int gq = q0 + wid * 16 + l16;
    if (quad == 0 && gq < NTOK)
        lpart[((size_t)ks * 12 + bh) * NTOK + gq] = l;

    // store unnormalized partials: wave-linear OP layout, 512 B per store
    __bf16* op = opart + ((((size_t)(ks * 12 + bh) * NQB + qb) * 8 + wid) * 1024);
    #pragma unroll
    for (int dt = 0; dt < 4; dt++) {
        bf16x4 pk = { (__bf16)oaccT[dt][0], (__bf16)oaccT[dt][1],
                      (__bf16)oaccT[dt][2], (__bf16)oaccT[dt][3] };
        *(bf16x4*)(op + (dt * 64 + lane) * 4) = pk;
    }
}

// ---------------------------------------------------------------------------
// k_comb: combine split-K partials (wave-linear OP layout) -> O bf16.
// ---------------------------------------------------------------------------
__global__ void k_comb(const __bf16* __restrict__ opart,
                       const float* __restrict__ lpart,
                       __bf16* __restrict__ o) {
    int idx = blockIdx.x * 256 + threadIdx.x;   // MTOT*96 total
    int token = idx / 96, rem = idx - token * 96;
    int c = rem * 4, h = c >> 6;
    int b2 = token / NTOK, n = token - b2 * NTOK;
    int bh = b2 * HEADS + h;
    // decode wave-linear OP coordinates (128 q/block, 16 q/wave)
    int qb = n >> 7, nb = n & 127;
    int wid = nb >> 4, l16 = nb & 15;
    int ch = c & 63, dt = ch >> 4, quad = (ch >> 2) & 3;
    int lane = quad * 16 + l16;
    size_t gbase = (((size_t)bh * NQB + qb) * 8 + wid) * 1024 + (dt * 64 + lane) * 4;
    const size_t kstride = (size_t)12 * NQB * 8 * 1024;   // elems per ks slice
    float a0 = 0.f, a1 = 0.f, a2 = 0.f, a3 = 0.f, l = 0.f;
    #pragma unroll
    for (int ks = 0; ks < KSPLIT; ks++) {
        bf16x4 p = *(const bf16x4*)&opart[(size_t)ks * kstride + gbase];
        a0 += (float)p[0]; a1 += (float)p[1]; a2 += (float)p[2]; a3 += (float)p[3];
        l += lpart[((size_t)ks * 12 + bh) * NTOK + n];
    }
    float inv = 1.f / l;
    bf16x4 ov = { (__bf16)(a0 * inv), (__bf16)(a1 * inv),
                  (__bf16)(a2 * inv), (__bf16)(a3 * inv) };
    *(bf16x4*)(o + (size_t)token * DIM + c) = ov;
}

// ---------------------------------------------------------------------------
extern "C" void kernel_launch(void* const* d_in, const int* in_sizes, int n_in,
                              void* d_out, int out_size, void* d_ws, size_t ws_size,
                              hipStream_t stream) {
    const float* x      = (const float*)d_in[0];
    const float* conv_w = (const float*)d_in[1];
    // d_in[2] conv_b cancels in reference
    const float* ln1_w  = (const float*)d_in[3];
    const float* ln1_b  = (const float*)d_in[4];
    const float* qkv_w  = (const float*)d_in[5];
    const float* proj_w = (const float*)d_in[6];
    const float* proj_b = (const float*)d_in[7];
    const float* ln2_w  = (const float*)d_in[8];
    const float* ln2_b  = (const float*)d_in[9];
    const float* fc1_w  = (const float*)d_in[10];
    const float* fc1_b  = (const float*)d_in[11];
    const float* fc2_w  = (const float*)d_in[12];
    const float* fc2_b  = (const float*)d_in[13];
    float* out = (float*)d_out;

    char* p = (char*)d_ws;
    float*  T    = (float*)p;  p += (size_t)MTOT * DIM * 4;           //  8.4 MB
    __bf16* TN   = (__bf16*)p; p += (size_t)MTOT * DIM * 2;           //  4.2 MB
    __bf16* QKV  = (__bf16*)p; p += (size_t)MTOT * 1152 * 2;          // 12.6 MB
    __bf16* VT   = (__bf16*)p; p += (size_t)BATCH * DIM * NTOKP * 2;  //  4.2 MB
    __bf16* O    = (__bf16*)p; p += (size_t)MTOT * DIM * 2;           //  4.2 MB
    __bf16* H    = (__bf16*)p; p += (size_t)MTOT * HIDDEN * 2;        // 16.9 MB
    __bf16* WQ   = (__bf16*)p; p += (size_t)1152 * 384 * 2;
    __bf16* WP   = (__bf16*)p; p += (size_t)384 * 384 * 2;
    __bf16* W1   = (__bf16*)p; p += (size_t)1536 * 384 * 2;
    __bf16* W2   = (__bf16*)p; p += (size_t)384 * 1536 * 2;
    float*  LP   = (float*)p;  p += (size_t)KSPLIT * 12 * NTOK * 4;   //  0.5 MB
    __bf16* OP   = (__bf16*)p; p += (size_t)KSPLIT * 12 * NQB * 8 * 1024 * 2; // 17.3 MB

    // 1. conv positional embedding + residual + weight cvt + VT pad zero
    k_conv<<<528 + 1728 + 1, 256, 0, stream>>>(
        x, conv_w, T, qkv_w, proj_w, fc1_w, fc2_w, WQ, WP, W1, W2, VT);
    // 2. LN1 -> bf16
    k_ln1<<<MTOT / 4, 256, 0, stream>>>(T, TN, ln1_w, ln1_b);
    // 3. QKV gemm (128x128 tile): Q pre-scaled; V -> VT2
    k_qkv<<<dim3(9, 43), 256, 0, stream>>>(TN, WQ, QKV, VT, MTOT, 1152, 384);
    // 4. attention split-K partials (zero-LDS softmax) + combine
    k_attn<<<NQB * 12 * KSPLIT, 512, 0, stream>>>(QKV, VT, OP, LP);
    k_comb<<<(MTOT * 96) / 256, 256, 0, stream>>>(OP, LP, O);
    // 5. T += O @ proj_w^T + proj_b (128x64 tile)
    k_proj<<<dim3(6, 43), 256, 0, stream>>>(O, WP, proj_b, T, T, MTOT, 384, 384);
    // 6. LN2 -> bf16
    k_ln2<<<MTOT / 4, 256, 0, stream>>>(T, TN, ln2_w, ln2_b);
    // 7. H = gelu(TN @ fc1_w^T + fc1_b) bf16 (128x128 tile)
    k_fc1<<<dim3(12, 43), 256, 0, stream>>>(TN, W1, fc1_b, H, MTOT, 1536, 384);
    // 8. out[b,c,n] = T + H @ fc2_w^T + fc2_b (LDS-transposed coalesced store)
    k_fc2<<<dim3(6, 86), 256, 0, stream>>>(H, W2, fc2_b, T, out, MTOT, 384, 1536);
}

// Round 10
// 233.820 us; speedup vs baseline: 1.0163x; 1.0163x over previous
//
#include <hip/hip_runtime.h>
#include <hip/hip_bf16.h>
#include <math.h>

#define DIM 384
#define HEADS 6
#define HIDDEN 1536
#define NTOK 2744   // 14*14*14
#define NTOKP 2752  // 43*64, padded key stride for VT
#define BATCH 2
#define MTOT (BATCH * NTOK)   // 5488
#define KSPLIT 4
#define NQB 22      // ceil(2744/128)  (128 queries per attn block)
#define CEXP 0.18033688f   // (1/8) * log2(e)

typedef __bf16 bf16x8 __attribute__((ext_vector_type(8)));
typedef __bf16 bf16x4 __attribute__((ext_vector_type(4)));
typedef float  f32x4  __attribute__((ext_vector_type(4)));

#define F_GELU  1
#define F_RESID 2
#define F_BF16  4
#define F_QKV   8
#define F_TRANS 16

// async global->LDS, 16B per lane; LDS dest = uniform base + lane*16
__device__ __forceinline__ void gll16(const void* g, void* l) {
    __builtin_amdgcn_global_load_lds(
        (const __attribute__((address_space(1))) unsigned int*)g,
        (__attribute__((address_space(3))) unsigned int*)l, 16, 0, 0);
}

// ---------------------------------------------------------------------------
// k_conv: depthwise conv3d (+residual) with WRITE-COMBINED output.
// Tail blocks: weight fp32->bf16 conversion (1728) + VT pad zeroing (1).
// ---------------------------------------------------------------------------
__global__ void k_conv(const float* __restrict__ x, const float* __restrict__ cw,
                       float* __restrict__ t,
                       const float* __restrict__ w0, const float* __restrict__ w1,
                       const float* __restrict__ w2, const float* __restrict__ w3,
                       __bf16* o0, __bf16* o1, __bf16* o2, __bf16* o3,
                       __bf16* vt_pad) {
    int bid = blockIdx.x;
    if (bid >= 2256) {   // ---- VT pad zeroing: slots p=11,15 of tile 42 ----
        #pragma unroll
        for (int k = 0; k < 6; k++) {
            int idx = k * 256 + threadIdx.x;   // 0..1535
            int row = idx >> 1, half = idx & 1;
            bf16x4 z4 = { (__bf16)0.f, (__bf16)0.f, (__bf16)0.f, (__bf16)0.f };
            *(bf16x4*)(vt_pad + (size_t)row * NTOKP + 2732 + half * 16) = z4;
        }
        return;
    }
    if (bid >= 528) {   // ---- weight conversion ----
        int i = (bid - 528) * 256 + threadIdx.x;   // float4 index
        const float* s; __bf16* d; int off;
        if (i < 110592)      { s = w0; d = o0; off = i; }
        else if (i < 147456) { s = w1; d = o1; off = i - 110592; }
        else if (i < 294912) { s = w2; d = o2; off = i - 147456; }
        else                 { s = w3; d = o3; off = i - 294912; }
        float4 v = ((const float4*)s)[off];
        bf16x4 bb = { (__bf16)v.x, (__bf16)v.y, (__bf16)v.z, (__bf16)v.w };
        *(bf16x4*)(d + (size_t)off * 4) = bb;
        return;
    }
    int nb = bid % 11, rest = bid / 11;
    int cb = rest % 24, b = rest / 24;
    int c0 = cb * 16;
    int n = nb * 256 + threadIdx.x;
    if (n >= NTOK) return;
    int d = n / 196, r = n % 196, h = r / 14, w = r % 14;
    const float* xb = x + ((size_t)b * DIM + c0) * NTOK;
    float acc[16];
    #pragma unroll
    for (int c = 0; c < 16; c++) acc[c] = xb[(size_t)c * NTOK + n];   // residual
    #pragma unroll
    for (int kd = 0; kd < 3; kd++) {
        int dd = d + kd - 1;
        if (dd < 0 || dd >= 14) continue;
        #pragma unroll
        for (int kh = 0; kh < 3; kh++) {
            int hh = h + kh - 1;
            if (hh < 0 || hh >= 14) continue;
            #pragma unroll
            for (int kw = 0; kw < 3; kw++) {
                int ww = w + kw - 1;
                if (ww < 0 || ww >= 14) continue;
                int np = (dd * 14 + hh) * 14 + ww;
                int tap = kd * 9 + kh * 3 + kw;
                #pragma unroll
                for (int c = 0; c < 16; c++)   // weight idx block-uniform -> s_load
                    acc[c] = fmaf(cw[(c0 + c) * 27 + tap], xb[(size_t)c * NTOK + np], acc[c]);
            }
        }
    }
    float* tp = t + (size_t)(b * NTOK + n) * DIM + c0;   // 64 B aligned line
    #pragma unroll
    for (int c = 0; c < 16; c += 4) {
        float4 v = { acc[c], acc[c + 1], acc[c + 2], acc[c + 3] };
        *(float4*)(tp + c) = v;
    }
}

// ---------------------------------------------------------------------------
// k_ln1 / k_ln2: LayerNorm fp32 in -> bf16 out. One wave per token.
// ---------------------------------------------------------------------------
__device__ __forceinline__ void ln_body(const float* __restrict__ in,
                                        __bf16* __restrict__ out,
                                        const float* __restrict__ w,
                                        const float* __restrict__ b) {
    int wid = threadIdx.x >> 6, lane = threadIdx.x & 63;
    int token = blockIdx.x * 4 + wid;
    const float* row = in + (size_t)token * DIM;
    float v[6], s = 0.f, s2 = 0.f;
    #pragma unroll
    for (int i = 0; i < 6; i++) {
        v[i] = row[lane + 64 * i];
        s += v[i]; s2 += v[i] * v[i];
    }
    #pragma unroll
    for (int m = 1; m < 64; m <<= 1) { s += __shfl_xor(s, m); s2 += __shfl_xor(s2, m); }
    float mu = s * (1.f / DIM);
    float rstd = rsqrtf(s2 * (1.f / DIM) - mu * mu + 1e-5f);
    __bf16* orow = out + (size_t)token * DIM;
    #pragma unroll
    for (int i = 0; i < 6; i++) {
        int c = lane + 64 * i;
        orow[c] = (__bf16)((v[i] - mu) * rstd * w[c] + b[c]);
    }
}
__global__ void k_ln1(const float* in, __bf16* out, const float* w, const float* b) {
    ln_body(in, out, w, b);
}
__global__ void k_ln2(const float* in, __bf16* out, const float* w, const float* b) {
    ln_body(in, out, w, b);
}

// ---------------------------------------------------------------------------
// gemm 128x64x64, SINGLE-buffered (24 KB LDS — dbuf halves occupancy, nets
// negative; 128x128 tiles break block-count granularity at 256 CUs), XOR
// chunk swizzle. QKV / FC1 / PROJ. F_RESID: float out += resid (proj).
// V output goes to VT2.
// ---------------------------------------------------------------------------
__device__ __forceinline__ void gemm12864_body(
    const __bf16* __restrict__ A, const __bf16* __restrict__ B,
    const float* __restrict__ bias, const float* __restrict__ resid,
    void* __restrict__ out, __bf16* __restrict__ vt_out,
    int M, int N, int K, int flags) {
    __shared__ __bf16 As[128][64];   // 16 KB
    __shared__ __bf16 Bs[64][64];    //  8 KB
    int tid = threadIdx.x, lane = tid & 63, wid = tid >> 6;
    int quad = lane >> 4, l16 = lane & 15;
    int wm = wid & 1, wn = wid >> 1;
    int m0 = blockIdx.y * 128, n0 = blockIdx.x * 64;
    int x7 = l16 & 7;

    auto stage = [&](int k0) {
        #pragma unroll
        for (int i = 0; i < 4; i++) {
            int c = i * 256 + tid;
            int row = c >> 3, cc = (c & 7) ^ (row & 7);
            int gm = m0 + row; if (gm > M - 1) gm = M - 1;
            gll16(A + (size_t)gm * K + k0 + cc * 8, &As[0][0] + (size_t)c * 8);
        }
        #pragma unroll
        for (int i = 0; i < 2; i++) {
            int c = i * 256 + tid;
            int row = c >> 3, cc = (c & 7) ^ (row & 7);
            gll16(B + (size_t)(n0 + row) * K + k0 + cc * 8, &Bs[0][0] + (size_t)c * 8);
        }
    };

    f32x4 acc[4][2] = {};
    int nk = K >> 6;
    for (int ki = 0; ki < nk; ki++) {
        if (ki) __syncthreads();
        stage(ki << 6);
        __syncthreads();
        #pragma unroll
        for (int s = 0; s < 2; s++) {
            bf16x8 a[4], b[2];
            #pragma unroll
            for (int i = 0; i < 4; i++)
                a[i] = *(bf16x8*)&As[wm * 64 + i * 16 + l16][(((s * 4 + quad) ^ x7)) * 8];
            #pragma unroll
            for (int j = 0; j < 2; j++)
                b[j] = *(bf16x8*)&Bs[wn * 32 + j * 16 + l16][(((s * 4 + quad) ^ x7)) * 8];
            #pragma unroll
            for (int i = 0; i < 4; i++)
                #pragma unroll
                for (int j = 0; j < 2; j++)
                    acc[i][j] = __builtin_amdgcn_mfma_f32_16x16x32_bf16(a[i], b[j], acc[i][j], 0, 0, 0);
        }
    }

    int colb = n0 + wn * 32;
    #pragma unroll
    for (int j = 0; j < 2; j++) {
        int col = colb + j * 16 + l16;
        float bv = bias ? bias[col] : 0.f;
        #pragma unroll
        for (int i = 0; i < 4; i++) {
            int row0 = m0 + wm * 64 + i * 16 + quad * 4;
            if (row0 >= M) continue;
            float v4[4];
            #pragma unroll
            for (int r = 0; r < 4; r++) {
                float v = acc[i][j][r] + bv;
                if (flags & F_GELU) v = 0.5f * v * (1.f + erff(v * 0.70710678f));
                if ((flags & F_QKV) && col < 384) v *= CEXP;   // pre-scale Q
                v4[r] = v;
            }
            if ((flags & F_QKV) && col >= 768) {
                int b2 = row0 / NTOK, n2 = row0 - b2 * NTOK;
                // t/q-swap within 64-key tile: k' = q*16 + t*4 + r
                int n2p = (n2 & ~63) | (((n2 >> 2) & 3) << 4) | (((n2 >> 4) & 3) << 2);
                bf16x4 pk = { (__bf16)v4[0], (__bf16)v4[1], (__bf16)v4[2], (__bf16)v4[3] };
                *(bf16x4*)(vt_out + ((size_t)(b2 * DIM + (col - 768))) * NTOKP + n2p) = pk;
            } else if (flags & F_RESID) {
                #pragma unroll
                for (int r = 0; r < 4; r++)
                    ((float*)out)[(size_t)(row0 + r) * N + col] =
                        v4[r] + resid[(size_t)(row0 + r) * N + col];
            } else {
                #pragma unroll
                for (int r = 0; r < 4; r++)
                    ((__bf16*)out)[(size_t)(row0 + r) * N + col] = (__bf16)v4[r];
            }
        }
    }
}
__global__ __launch_bounds__(256) void k_qkv(const __bf16* A, const __bf16* B,
        void* out, __bf16* vt_out, int M, int N, int K) {
    gemm12864_body(A, B, nullptr, nullptr, out, vt_out, M, N, K, F_QKV);
}
__global__ __launch_bounds__(256) void k_fc1(const __bf16* A, const __bf16* B,
        const float* bias, void* out, int M, int N, int K) {
    gemm12864_body(A, B, bias, nullptr, out, nullptr, M, N, K, F_GELU | F_BF16);
}
__global__ __launch_bounds__(256) void k_proj(const __bf16* A, const __bf16* B,
        const float* bias, const float* resid, void* out, int M, int N, int K) {
    gemm12864_body(A, B, bias, resid, out, nullptr, M, N, K, F_RESID);
}

// ---------------------------------------------------------------------------
// gemm 64x64x64, SINGLE-buffered, fc2 only. F_TRANS path does an LDS
// transpose (two 32-col halves, [32][68] fp32) so the out[b,c,n] store is
// 256 B-contiguous coalesced.
// ---------------------------------------------------------------------------
__device__ __forceinline__ void gemm64_body(
    const __bf16* __restrict__ A, const __bf16* __restrict__ B,
    const float* __restrict__ bias, const float* __restrict__ resid,
    void* __restrict__ out, int M, int N, int K, int flags) {
    __shared__ __align__(16) char sm[17408];   // As 8K @0, Bs 8K @8192; Tt reuse
    __bf16 (*As)[64] = (__bf16(*)[64])sm;
    __bf16 (*Bs)[64] = (__bf16(*)[64])(sm + 8192);
    float* Tt = (float*)sm;                    // [32][68] fp32 = 8704 B
    int tid = threadIdx.x, lane = tid & 63, wid = tid >> 6;
    int quad = lane >> 4, l16 = lane & 15;
    int wm = wid & 1, wn = wid >> 1;
    int m0 = blockIdx.y * 64, n0 = blockIdx.x * 64;
    int x7 = l16 & 7;

    auto stage = [&](int k0) {
        #pragma unroll
        for (int i = 0; i < 2; i++) {
            int c = i * 256 + tid;
            int row = c >> 3, cc = (c & 7) ^ (row & 7);
            int gm = m0 + row; if (gm > M - 1) gm = M - 1;
            gll16(A + (size_t)gm * K + k0 + cc * 8, &As[0][0] + (size_t)c * 8);
        }
        #pragma unroll
        for (int i = 0; i < 2; i++) {
            int c = i * 256 + tid;
            int row = c >> 3, cc = (c & 7) ^ (row & 7);
            gll16(B + (size_t)(n0 + row) * K + k0 + cc * 8, &Bs[0][0] + (size_t)c * 8);
        }
    };

    f32x4 acc[2][2] = {};
    int nk = K >> 6;
    for (int ki = 0; ki < nk; ki++) {
        if (ki) __syncthreads();
        stage(ki << 6);
        __syncthreads();
        #pragma unroll
        for (int s = 0; s < 2; s++) {
            bf16x8 a[2], b[2];
            #pragma unroll
            for (int i = 0; i < 2; i++)
                a[i] = *(bf16x8*)&As[wm * 32 + i * 16 + l16][(((s * 4 + quad) ^ x7)) * 8];
            #pragma unroll
            for (int j = 0; j < 2; j++)
                b[j] = *(bf16x8*)&Bs[wn * 32 + j * 16 + l16][(((s * 4 + quad) ^ x7)) * 8];
            #pragma unroll
            for (int i = 0; i < 2; i++)
                #pragma unroll
                for (int j = 0; j < 2; j++)
                    acc[i][j] = __builtin_amdgcn_mfma_f32_16x16x32_bf16(a[i], b[j], acc[i][j], 0, 0, 0);
        }
    }

    if (flags & F_TRANS) {
        // coalesced transposed store via LDS, two 32-col halves
        #pragma unroll
        for (int half = 0; half < 2; half++) {
            __syncthreads();   // staging (or prior half) reads done
            if (wn == half) {
                #pragma unroll
                for (int j = 0; j < 2; j++) {
                    int colL = j * 16 + l16;                 // 0..31 in half
                    int col = n0 + half * 32 + colL;
                    float bv = bias[col];
                    #pragma unroll
                    for (int i = 0; i < 2; i++) {
                        int rowL = wm * 32 + i * 16 + quad * 4;
                        float v4[4];
                        #pragma unroll
                        for (int r = 0; r < 4; r++) {
                            int rr = m0 + rowL + r; if (rr > M - 1) rr = M - 1;
                            v4[r] = acc[i][j][r] + bv + resid[(size_t)rr * N + col];
                        }
                        float4 pk = { v4[0], v4[1], v4[2], v4[3] };
                        *(float4*)&Tt[colL * 68 + rowL] = pk;
                    }
                }
            }
            __syncthreads();
            int c = tid >> 3, no = (tid & 7) * 8;
            int col = n0 + half * 32 + c;
            #pragma unroll
            for (int q2 = 0; q2 < 2; q2++) {
                int nn = no + q2 * 4;
                int row = m0 + nn;
                if (row >= M) continue;
                int b2 = row / NTOK, n2 = row - b2 * NTOK;
                float4 v = *(float4*)&Tt[c * 68 + nn];
                *(float4*)((float*)out + ((size_t)(b2 * N + col)) * NTOK + n2) = v;
            }
        }
        return;
    }

    #pragma unroll
    for (int j = 0; j < 2; j++) {
        int col = n0 + wn * 32 + j * 16 + l16;
        float bv = bias ? bias[col] : 0.f;
        #pragma unroll
        for (int i = 0; i < 2; i++) {
            int row0 = m0 + wm * 32 + i * 16 + quad * 4;
            if (row0 >= M) continue;
            #pragma unroll
            for (int r = 0; r < 4; r++) {
                float v = acc[i][j][r] + bv;
                if (flags & F_RESID) v += resid[(size_t)(row0 + r) * N + col];
                ((float*)out)[(size_t)(row0 + r) * N + col] = v;
            }
        }
    }
}
__global__ __launch_bounds__(256) void k_fc2(const __bf16* A, const __bf16* B,
        const float* bias, const float* resid, void* out, int M, int N, int K) {
    gemm64_body(A, B, bias, resid, out, M, N, K, F_RESID | F_TRANS);
}

// ---------------------------------------------------------------------------
// k_attn (best measured 48.6us): zero-LDS softmax, 8 waves x 16 q,
// KSPLIT=4, grid 1056 (4.1 blocks/CU), VT2 b128 PV, wave-linear OP stores,
// XCD grouping. setprio kept (null but harmless).
// ---------------------------------------------------------------------------
__global__ __launch_bounds__(512, 8) void k_attn(const __bf16* __restrict__ qkv,
                                                 const __bf16* __restrict__ vt,
                                                 __bf16* __restrict__ opart,
                                                 float* __restrict__ lpart) {
    __shared__ __align__(16) __bf16 KV[2][2][64][64];   // 32 KB: [buf][K/V][row][col]
    __bf16 (*Qs)[64] = (__bf16(*)[64])KV;               // 16 KB overlay (= buf0)

    int tid = threadIdx.x, lane = tid & 63, wid = tid >> 6;
    int quad = lane >> 4, l16 = lane & 15;
    // XCD-aware remap: flat%8 = XCD (round-robin dispatch); same (bh,ks) -> one XCD
    int flat = blockIdx.x;
    int xcd = flat & 7, slot = flat >> 3;     // slot 0..131
    int grp = slot / NQB, qb = slot - grp * NQB;
    int g = xcd + 8 * grp;                    // 0..47
    int bh = g % 12, ks = g / 12;
    int q0 = qb * 128;
    int b = bh / HEADS, h = bh % HEADS;
    int x7 = l16 & 7;

    int kt0 = (43 * ks) / KSPLIT, kt1 = (43 * (ks + 1)) / KSPLIT;

    // per-thread staging geometry: one gll16 each for K and V per tile
    int srow = tid >> 3, scc = (tid & 7) ^ (srow & 7);
    const __bf16* pK = qkv + ((size_t)(b * NTOK + kt0 * 64 + srow)) * 1152 + 384 + h * 64 + scc * 8;
    const __bf16* pV = vt + ((size_t)(bh * 64 + srow)) * NTOKP + kt0 * 64 + scc * 8;

    auto stageKV = [&](int kt, int bufi) {
        const __bf16* kp = pK + (size_t)(kt - kt0) * (64 * 1152);
        if (kt == 42 && srow >= 56)   // clamp tail rows (keys >= NTOK)
            kp = qkv + ((size_t)(b * NTOK + NTOK - 1)) * 1152 + 384 + h * 64 + scc * 8;
        gll16(kp, &KV[bufi][0][0][0] + (size_t)tid * 8);
        gll16(pV + (size_t)(kt - kt0) * 64, &KV[bufi][1][0][0] + (size_t)tid * 8);
    };

    // ---- prologue: stage Q (128 rows = 1024 granules) into the buf0 overlay ----
    #pragma unroll
    for (int i = 0; i < 2; i++) {
        int c = i * 512 + tid;
        int row = c >> 3, cc = (c & 7) ^ (row & 7);
        int gq = q0 + row; if (gq > NTOK - 1) gq = NTOK - 1;
        gll16(qkv + ((size_t)(b * NTOK + gq)) * 1152 + h * 64 + cc * 8,
              &Qs[0][0] + (size_t)c * 8);
    }
    __syncthreads();   // Q staged

    bf16x8 aq[2];
    #pragma unroll
    for (int sx = 0; sx < 2; sx++)
        aq[sx] = *(bf16x8*)&Qs[wid * 16 + l16][((sx * 4 + quad) ^ x7) * 8];
    __syncthreads();   // all waves done reading Qs before buf0 overwrite

    stageKV(kt0, 0);

    // lane-constant LDS read offsets (elements)
    int koff0 = (quad ^ x7) * 8, koff1 = ((4 + quad) ^ x7) * 8;
    int voff0 = ((quad * 2 + 0) ^ x7) * 8, voff1 = ((quad * 2 + 1) ^ x7) * 8;

    const f32x4 fzero = {0.f, 0.f, 0.f, 0.f};
    f32x4 oaccT[4] = {};   // O^T: row d = dt*16+quad*4+r, col q = l16
    float l_sum = 0.f;

    int bufi = 0;
    for (int kt = kt0; kt < kt1; kt++) {
        __syncthreads();                          // stage(kt) landed; prev readers done
        if (kt + 1 < kt1) stageKV(kt + 1, bufi ^ 1);   // prefetch next tile

        const __bf16* ksb = &KV[bufi][0][0][0] + l16 * 64;
        const __bf16* vtb = &KV[bufi][1][0][0] + l16 * 64;
        bool tail = (kt == 42);

        // S^T per 16-key block t; exp in-register -> pb B-fragments (no LDS)
        bf16x8 pb[2];
        #pragma unroll
        for (int t = 0; t < 4; t++) {
            bf16x8 bk0 = *(bf16x8*)(ksb + t * 1024 + koff0);
            bf16x8 bk1 = *(bf16x8*)(ksb + t * 1024 + koff1);
            __builtin_amdgcn_s_setprio(1);
            f32x4 z = __builtin_amdgcn_mfma_f32_16x16x32_bf16(bk0, aq[0], fzero, 0, 0, 0);
            z = __builtin_amdgcn_mfma_f32_16x16x32_bf16(bk1, aq[1], z, 0, 0, 0);
            __builtin_amdgcn_s_setprio(0);
            float e0 = exp2f(z[0]), e1 = exp2f(z[1]), e2 = exp2f(z[2]), e3 = exp2f(z[3]);
            if (tail) {
                int kb = kt * 64 + t * 16 + quad * 4;
                if (kb + 0 >= NTOK) e0 = 0.f;
                if (kb + 1 >= NTOK) e1 = 0.f;
                if (kb + 2 >= NTOK) e2 = 0.f;
                if (kb + 3 >= NTOK) e3 = 0.f;
            }
            l_sum += (e0 + e1) + (e2 + e3);
            int half = (t & 1) * 4, px = t >> 1;
            pb[px][half + 0] = (__bf16)e0;
            pb[px][half + 1] = (__bf16)e1;
            pb[px][half + 2] = (__bf16)e2;
            pb[px][half + 3] = (__bf16)e3;
        }

        // PV: per (dt,sx) ONE contiguous b128 V^T fragment (VT2 layout), 2 MFMA
        __builtin_amdgcn_s_setprio(1);
        #pragma unroll
        for (int dt = 0; dt < 4; dt++) {
            const __bf16* vr = vtb + dt * 1024;
            bf16x8 av0 = *(bf16x8*)(vr + voff0);
            bf16x8 av1 = *(bf16x8*)(vr + voff1);
            oaccT[dt] = __builtin_amdgcn_mfma_f32_16x16x32_bf16(av0, pb[0], oaccT[dt], 0, 0, 0);
            oaccT[dt] = __builtin_amdgcn_mfma_f32_16x16x32_bf16(av1, pb[1], oaccT[dt], 0, 0, 0);
        }
        __builtin_amdgcn_s_setprio(0);
        bufi ^= 1;
    }

    // softmax denominator: per-lane partials, reduce across quads (2 shuffles)
    float l = l_sum;
    l += __shfl_xor(l, 16);
    l += __shfl_xor(l, 32);
    int gq = q0 + wid * 16 + l16;
    if (quad == 0 && gq < NTOK)
        lpart[((size_t)ks * 12 + bh) * NTOK + gq] = l;

    // store unnormalized partials: wave-linear OP layout, 512 B per store
    __bf16* op = opart + ((((size_t)(ks * 12 + bh) * NQB + qb) * 8 + wid) * 1024);
    #pragma unroll
    for (int dt = 0; dt < 4; dt++) {
        bf16x4 pk = { (__bf16)oaccT[dt][0], (__bf16)oaccT[dt][1],
                      (__bf16)oaccT[dt][2], (__bf16)oaccT[dt][3] };
        *(bf16x4*)(op + (dt * 64 + lane) * 4) = pk;
    }
}

// ---------------------------------------------------------------------------
// k_comb: combine split-K partials (wave-linear OP layout) -> O bf16.
// ---------------------------------------------------------------------------
__global__ void k_comb(const __bf16* __restrict__ opart,
                       const float* __restrict__ lpart,
                       __bf16* __restrict__ o) {
    int idx = blockIdx.x * 256 + threadIdx.x;   // MTOT*96 total
    int token = idx / 96, rem = idx - token * 96;
    int c = rem * 4, h = c >> 6;
    int b2 = token / NTOK, n = token - b2 * NTOK;
    int bh = b2 * HEADS + h;
    // decode wave-linear OP coordinates (128 q/block, 16 q/wave)
    int qb = n >> 7, nb = n & 127;
    int wid = nb >> 4, l16 = nb & 15;
    int ch = c & 63, dt = ch >> 4, quad = (ch >> 2) & 3;
    int lane = quad * 16 + l16;
    size_t gbase = (((size_t)bh * NQB + qb) * 8 + wid) * 1024 + (dt * 64 + lane) * 4;
    const size_t kstride = (size_t)12 * NQB * 8 * 1024;   // elems per ks slice
    float a0 = 0.f, a1 = 0.f, a2 = 0.f, a3 = 0.f, l = 0.f;
    #pragma unroll
    for (int ks = 0; ks < KSPLIT; ks++) {
        bf16x4 p = *(const bf16x4*)&opart[(size_t)ks * kstride + gbase];
        a0 += (float)p[0]; a1 += (float)p[1]; a2 += (float)p[2]; a3 += (float)p[3];
        l += lpart[((size_t)ks * 12 + bh) * NTOK + n];
    }
    float inv = 1.f / l;
    bf16x4 ov = { (__bf16)(a0 * inv), (__bf16)(a1 * inv),
                  (__bf16)(a2 * inv), (__bf16)(a3 * inv) };
    *(bf16x4*)(o + (size_t)token * DIM + c) = ov;
}

// ---------------------------------------------------------------------------
extern "C" void kernel_launch(void* const* d_in, const int* in_sizes, int n_in,
                              void* d_out, int out_size, void* d_ws, size_t ws_size,
                              hipStream_t stream) {
    const float* x      = (const float*)d_in[0];
    const float* conv_w = (const float*)d_in[1];
    // d_in[2] conv_b cancels in reference
    const float* ln1_w  = (const float*)d_in[3];
    const float* ln1_b  = (const float*)d_in[4];
    const float* qkv_w  = (const float*)d_in[5];
    const float* proj_w = (const float*)d_in[6];
    const float* proj_b = (const float*)d_in[7];
    const float* ln2_w  = (const float*)d_in[8];
    const float* ln2_b  = (const float*)d_in[9];
    const float* fc1_w  = (const float*)d_in[10];
    const float* fc1_b  = (const float*)d_in[11];
    const float* fc2_w  = (const float*)d_in[12];
    const float* fc2_b  = (const float*)d_in[13];
    float* out = (float*)d_out;

    char* p = (char*)d_ws;
    float*  T    = (float*)p;  p += (size_t)MTOT * DIM * 4;           //  8.4 MB
    __bf16* TN   = (__bf16*)p; p += (size_t)MTOT * DIM * 2;           //  4.2 MB
    __bf16* QKV  = (__bf16*)p; p += (size_t)MTOT * 1152 * 2;          // 12.6 MB
    __bf16* VT   = (__bf16*)p; p += (size_t)BATCH * DIM * NTOKP * 2;  //  4.2 MB
    __bf16* O    = (__bf16*)p; p += (size_t)MTOT * DIM * 2;           //  4.2 MB
    __bf16* H    = (__bf16*)p; p += (size_t)MTOT * HIDDEN * 2;        // 16.9 MB
    __bf16* WQ   = (__bf16*)p; p += (size_t)1152 * 384 * 2;
    __bf16* WP   = (__bf16*)p; p += (size_t)384 * 384 * 2;
    __bf16* W1   = (__bf16*)p; p += (size_t)1536 * 384 * 2;
    __bf16* W2   = (__bf16*)p; p += (size_t)384 * 1536 * 2;
    float*  LP   = (float*)p;  p += (size_t)KSPLIT * 12 * NTOK * 4;   //  0.5 MB
    __bf16* OP   = (__bf16*)p; p += (size_t)KSPLIT * 12 * NQB * 8 * 1024 * 2; // 17.3 MB

    // 1. conv positional embedding + residual + weight cvt + VT pad zero
    k_conv<<<528 + 1728 + 1, 256, 0, stream>>>(
        x, conv_w, T, qkv_w, proj_w, fc1_w, fc2_w, WQ, WP, W1, W2, VT);
    // 2. LN1 -> bf16
    k_ln1<<<MTOT / 4, 256, 0, stream>>>(T, TN, ln1_w, ln1_b);
    // 3. QKV gemm (single-buffer): Q pre-scaled; V -> VT2
    k_qkv<<<dim3(18, 43), 256, 0, stream>>>(TN, WQ, QKV, VT, MTOT, 1152, 384);
    // 4. attention split-K partials (zero-LDS softmax + setprio) + combine
    k_attn<<<NQB * 12 * KSPLIT, 512, 0, stream>>>(QKV, VT, OP, LP);
    k_comb<<<(MTOT * 96) / 256, 256, 0, stream>>>(OP, LP, O);
    // 5. T += O @ proj_w^T + proj_b (128x64 tile: half the blocks/barriers)
    k_proj<<<dim3(6, 43), 256, 0, stream>>>(O, WP, proj_b, T, T, MTOT, 384, 384);
    // 6. LN2 -> bf16
    k_ln2<<<MTOT / 4, 256, 0, stream>>>(T, TN, ln2_w, ln2_b);
    // 7. H = gelu(TN @ fc1_w^T + fc1_b) bf16 (single-buffer)
    k_fc1<<<dim3(24, 43), 256, 0, stream>>>(TN, W1, fc1_b, H, MTOT, 1536, 384);
    // 8. out[b,c,n] = T + H @ fc2_w^T + fc2_b (LDS-transposed coalesced store)
    k_fc2<<<dim3(6, 86), 256, 0, stream>>>(H, W2, fc2_b, T, out, MTOT, 384, 1536);
}

// Round 11
// 230.969 us; speedup vs baseline: 1.0289x; 1.0123x over previous
//
#include <hip/hip_runtime.h>
#include <hip/hip_bf16.h>
#include <math.h>

#define DIM 384
#define HEADS 6
#define HIDDEN 1536
#define NTOK 2744   // 14*14*14
#define NTOKP 2752  // 43*64, padded key stride for VT
#define BATCH 2
#define MTOT (BATCH * NTOK)   // 5488
#define KSPLIT 4
#define NQB 22      // ceil(2744/128)  (128 queries per attn block)
#define CEXP 0.18033688f   // (1/8) * log2(e)

typedef __bf16 bf16x8 __attribute__((ext_vector_type(8)));
typedef __bf16 bf16x4 __attribute__((ext_vector_type(4)));
typedef float  f32x4  __attribute__((ext_vector_type(4)));

#define F_GELU  1
#define F_RESID 2
#define F_BF16  4
#define F_QKV   8
#define F_TRANS 16

// async global->LDS, 16B per lane; LDS dest = uniform base + lane*16
__device__ __forceinline__ void gll16(const void* g, void* l) {
    __builtin_amdgcn_global_load_lds(
        (const __attribute__((address_space(1))) unsigned int*)g,
        (__attribute__((address_space(3))) unsigned int*)l, 16, 0, 0);
}

// ---------------------------------------------------------------------------
// k_conv: depthwise conv3d (+residual) with WRITE-COMBINED output.
// Tail blocks: weight fp32->bf16 conversion (1728) + VT pad zeroing (1).
// ---------------------------------------------------------------------------
__global__ void k_conv(const float* __restrict__ x, const float* __restrict__ cw,
                       float* __restrict__ t,
                       const float* __restrict__ w0, const float* __restrict__ w1,
                       const float* __restrict__ w2, const float* __restrict__ w3,
                       __bf16* o0, __bf16* o1, __bf16* o2, __bf16* o3,
                       __bf16* vt_pad) {
    int bid = blockIdx.x;
    if (bid >= 2256) {   // ---- VT pad zeroing: slots p=11,15 of tile 42 ----
        #pragma unroll
        for (int k = 0; k < 6; k++) {
            int idx = k * 256 + threadIdx.x;   // 0..1535
            int row = idx >> 1, half = idx & 1;
            bf16x4 z4 = { (__bf16)0.f, (__bf16)0.f, (__bf16)0.f, (__bf16)0.f };
            *(bf16x4*)(vt_pad + (size_t)row * NTOKP + 2732 + half * 16) = z4;
        }
        return;
    }
    if (bid >= 528) {   // ---- weight conversion ----
        int i = (bid - 528) * 256 + threadIdx.x;   // float4 index
        const float* s; __bf16* d; int off;
        if (i < 110592)      { s = w0; d = o0; off = i; }
        else if (i < 147456) { s = w1; d = o1; off = i - 110592; }
        else if (i < 294912) { s = w2; d = o2; off = i - 147456; }
        else                 { s = w3; d = o3; off = i - 294912; }
        float4 v = ((const float4*)s)[off];
        bf16x4 bb = { (__bf16)v.x, (__bf16)v.y, (__bf16)v.z, (__bf16)v.w };
        *(bf16x4*)(d + (size_t)off * 4) = bb;
        return;
    }
    int nb = bid % 11, rest = bid / 11;
    int cb = rest % 24, b = rest / 24;
    int c0 = cb * 16;
    int n = nb * 256 + threadIdx.x;
    if (n >= NTOK) return;
    int d = n / 196, r = n % 196, h = r / 14, w = r % 14;
    const float* xb = x + ((size_t)b * DIM + c0) * NTOK;
    float acc[16];
    #pragma unroll
    for (int c = 0; c < 16; c++) acc[c] = xb[(size_t)c * NTOK + n];   // residual
    #pragma unroll
    for (int kd = 0; kd < 3; kd++) {
        int dd = d + kd - 1;
        if (dd < 0 || dd >= 14) continue;
        #pragma unroll
        for (int kh = 0; kh < 3; kh++) {
            int hh = h + kh - 1;
            if (hh < 0 || hh >= 14) continue;
            #pragma unroll
            for (int kw = 0; kw < 3; kw++) {
                int ww = w + kw - 1;
                if (ww < 0 || ww >= 14) continue;
                int np = (dd * 14 + hh) * 14 + ww;
                int tap = kd * 9 + kh * 3 + kw;
                #pragma unroll
                for (int c = 0; c < 16; c++)   // weight idx block-uniform -> s_load
                    acc[c] = fmaf(cw[(c0 + c) * 27 + tap], xb[(size_t)c * NTOK + np], acc[c]);
            }
        }
    }
    float* tp = t + (size_t)(b * NTOK + n) * DIM + c0;   // 64 B aligned line
    #pragma unroll
    for (int c = 0; c < 16; c += 4) {
        float4 v = { acc[c], acc[c + 1], acc[c + 2], acc[c + 3] };
        *(float4*)(tp + c) = v;
    }
}

// ---------------------------------------------------------------------------
// k_ln1 / k_ln2: LayerNorm fp32 in -> bf16 out. One wave per token.
// ---------------------------------------------------------------------------
__device__ __forceinline__ void ln_body(const float* __restrict__ in,
                                        __bf16* __restrict__ out,
                                        const float* __restrict__ w,
                                        const float* __restrict__ b) {
    int wid = threadIdx.x >> 6, lane = threadIdx.x & 63;
    int token = blockIdx.x * 4 + wid;
    const float* row = in + (size_t)token * DIM;
    float v[6], s = 0.f, s2 = 0.f;
    #pragma unroll
    for (int i = 0; i < 6; i++) {
        v[i] = row[lane + 64 * i];
        s += v[i]; s2 += v[i] * v[i];
    }
    #pragma unroll
    for (int m = 1; m < 64; m <<= 1) { s += __shfl_xor(s, m); s2 += __shfl_xor(s2, m); }
    float mu = s * (1.f / DIM);
    float rstd = rsqrtf(s2 * (1.f / DIM) - mu * mu + 1e-5f);
    __bf16* orow = out + (size_t)token * DIM;
    #pragma unroll
    for (int i = 0; i < 6; i++) {
        int c = lane + 64 * i;
        orow[c] = (__bf16)((v[i] - mu) * rstd * w[c] + b[c]);
    }
}
__global__ void k_ln1(const float* in, __bf16* out, const float* w, const float* b) {
    ln_body(in, out, w, b);
}
__global__ void k_ln2(const float* in, __bf16* out, const float* w, const float* b) {
    ln_body(in, out, w, b);
}

// ---------------------------------------------------------------------------
// gemm 128x64x64, SINGLE-buffered (24 KB LDS — dbuf halves occupancy, nets
// negative; 128x128 tiles break block-count granularity at 256 CUs), XOR
// chunk swizzle. QKV / FC1 / PROJ. F_RESID: float out += resid (proj).
// V output goes to VT2.
// ---------------------------------------------------------------------------
__device__ __forceinline__ void gemm12864_body(
    const __bf16* __restrict__ A, const __bf16* __restrict__ B,
    const float* __restrict__ bias, const float* __restrict__ resid,
    void* __restrict__ out, __bf16* __restrict__ vt_out,
    int M, int N, int K, int flags) {
    __shared__ __bf16 As[128][64];   // 16 KB
    __shared__ __bf16 Bs[64][64];    //  8 KB
    int tid = threadIdx.x, lane = tid & 63, wid = tid >> 6;
    int quad = lane >> 4, l16 = lane & 15;
    int wm = wid & 1, wn = wid >> 1;
    int m0 = blockIdx.y * 128, n0 = blockIdx.x * 64;
    int x7 = l16 & 7;

    auto stage = [&](int k0) {
        #pragma unroll
        for (int i = 0; i < 4; i++) {
            int c = i * 256 + tid;
            int row = c >> 3, cc = (c & 7) ^ (row & 7);
            int gm = m0 + row; if (gm > M - 1) gm = M - 1;
            gll16(A + (size_t)gm * K + k0 + cc * 8, &As[0][0] + (size_t)c * 8);
        }
        #pragma unroll
        for (int i = 0; i < 2; i++) {
            int c = i * 256 + tid;
            int row = c >> 3, cc = (c & 7) ^ (row & 7);
            gll16(B + (size_t)(n0 + row) * K + k0 + cc * 8, &Bs[0][0] + (size_t)c * 8);
        }
    };

    f32x4 acc[4][2] = {};
    int nk = K >> 6;
    for (int ki = 0; ki < nk; ki++) {
        if (ki) __syncthreads();
        stage(ki << 6);
        __syncthreads();
        #pragma unroll
        for (int s = 0; s < 2; s++) {
            bf16x8 a[4], b[2];
            #pragma unroll
            for (int i = 0; i < 4; i++)
                a[i] = *(bf16x8*)&As[wm * 64 + i * 16 + l16][(((s * 4 + quad) ^ x7)) * 8];
            #pragma unroll
            for (int j = 0; j < 2; j++)
                b[j] = *(bf16x8*)&Bs[wn * 32 + j * 16 + l16][(((s * 4 + quad) ^ x7)) * 8];
            #pragma unroll
            for (int i = 0; i < 4; i++)
                #pragma unroll
                for (int j = 0; j < 2; j++)
                    acc[i][j] = __builtin_amdgcn_mfma_f32_16x16x32_bf16(a[i], b[j], acc[i][j], 0, 0, 0);
        }
    }

    int colb = n0 + wn * 32;
    #pragma unroll
    for (int j = 0; j < 2; j++) {
        int col = colb + j * 16 + l16;
        float bv = bias ? bias[col] : 0.f;
        #pragma unroll
        for (int i = 0; i < 4; i++) {
            int row0 = m0 + wm * 64 + i * 16 + quad * 4;
            if (row0 >= M) continue;
            float v4[4];
            #pragma unroll
            for (int r = 0; r < 4; r++) {
                float v = acc[i][j][r] + bv;
                if (flags & F_GELU) v = 0.5f * v * (1.f + erff(v * 0.70710678f));
                if ((flags & F_QKV) && col < 384) v *= CEXP;   // pre-scale Q
                v4[r] = v;
            }
            if ((flags & F_QKV) && col >= 768) {
                int b2 = row0 / NTOK, n2 = row0 - b2 * NTOK;
                // t/q-swap within 64-key tile: k' = q*16 + t*4 + r
                int n2p = (n2 & ~63) | (((n2 >> 2) & 3) << 4) | (((n2 >> 4) & 3) << 2);
                bf16x4 pk = { (__bf16)v4[0], (__bf16)v4[1], (__bf16)v4[2], (__bf16)v4[3] };
                *(bf16x4*)(vt_out + ((size_t)(b2 * DIM + (col - 768))) * NTOKP + n2p) = pk;
            } else if (flags & F_RESID) {
                #pragma unroll
                for (int r = 0; r < 4; r++)
                    ((float*)out)[(size_t)(row0 + r) * N + col] =
                        v4[r] + resid[(size_t)(row0 + r) * N + col];
            } else {
                #pragma unroll
                for (int r = 0; r < 4; r++)
                    ((__bf16*)out)[(size_t)(row0 + r) * N + col] = (__bf16)v4[r];
            }
        }
    }
}
__global__ __launch_bounds__(256) void k_qkv(const __bf16* A, const __bf16* B,
        void* out, __bf16* vt_out, int M, int N, int K) {
    gemm12864_body(A, B, nullptr, nullptr, out, vt_out, M, N, K, F_QKV);
}
__global__ __launch_bounds__(256) void k_fc1(const __bf16* A, const __bf16* B,
        const float* bias, void* out, int M, int N, int K) {
    gemm12864_body(A, B, bias, nullptr, out, nullptr, M, N, K, F_GELU | F_BF16);
}
__global__ __launch_bounds__(256) void k_proj(const __bf16* A, const __bf16* B,
        const float* bias, const float* resid, void* out, int M, int N, int K) {
    gemm12864_body(A, B, bias, resid, out, nullptr, M, N, K, F_RESID);
}

// ---------------------------------------------------------------------------
// gemm 64x64x64, SINGLE-buffered, fc2 only. F_TRANS path does an LDS
// transpose (two 32-col halves, [32][68] fp32) so the out[b,c,n] store is
// 256 B-contiguous coalesced.
// ---------------------------------------------------------------------------
__device__ __forceinline__ void gemm64_body(
    const __bf16* __restrict__ A, const __bf16* __restrict__ B,
    const float* __restrict__ bias, const float* __restrict__ resid,
    void* __restrict__ out, int M, int N, int K, int flags) {
    __shared__ __align__(16) char sm[17408];   // As 8K @0, Bs 8K @8192; Tt reuse
    __bf16 (*As)[64] = (__bf16(*)[64])sm;
    __bf16 (*Bs)[64] = (__bf16(*)[64])(sm + 8192);
    float* Tt = (float*)sm;                    // [32][68] fp32 = 8704 B
    int tid = threadIdx.x, lane = tid & 63, wid = tid >> 6;
    int quad = lane >> 4, l16 = lane & 15;
    int wm = wid & 1, wn = wid >> 1;
    int m0 = blockIdx.y * 64, n0 = blockIdx.x * 64;
    int x7 = l16 & 7;

    auto stage = [&](int k0) {
        #pragma unroll
        for (int i = 0; i < 2; i++) {
            int c = i * 256 + tid;
            int row = c >> 3, cc = (c & 7) ^ (row & 7);
            int gm = m0 + row; if (gm > M - 1) gm = M - 1;
            gll16(A + (size_t)gm * K + k0 + cc * 8, &As[0][0] + (size_t)c * 8);
        }
        #pragma unroll
        for (int i = 0; i < 2; i++) {
            int c = i * 256 + tid;
            int row = c >> 3, cc = (c & 7) ^ (row & 7);
            gll16(B + (size_t)(n0 + row) * K + k0 + cc * 8, &Bs[0][0] + (size_t)c * 8);
        }
    };

    f32x4 acc[2][2] = {};
    int nk = K >> 6;
    for (int ki = 0; ki < nk; ki++) {
        if (ki) __syncthreads();
        stage(ki << 6);
        __syncthreads();
        #pragma unroll
        for (int s = 0; s < 2; s++) {
            bf16x8 a[2], b[2];
            #pragma unroll
            for (int i = 0; i < 2; i++)
                a[i] = *(bf16x8*)&As[wm * 32 + i * 16 + l16][(((s * 4 + quad) ^ x7)) * 8];
            #pragma unroll
            for (int j = 0; j < 2; j++)
                b[j] = *(bf16x8*)&Bs[wn * 32 + j * 16 + l16][(((s * 4 + quad) ^ x7)) * 8];
            #pragma unroll
            for (int i = 0; i < 2; i++)
                #pragma unroll
                for (int j = 0; j < 2; j++)
                    acc[i][j] = __builtin_amdgcn_mfma_f32_16x16x32_bf16(a[i], b[j], acc[i][j], 0, 0, 0);
        }
    }

    if (flags & F_TRANS) {
        // coalesced transposed store via LDS, two 32-col halves
        #pragma unroll
        for (int half = 0; half < 2; half++) {
            __syncthreads();   // staging (or prior half) reads done
            if (wn == half) {
                #pragma unroll
                for (int j = 0; j < 2; j++) {
                    int colL = j * 16 + l16;                 // 0..31 in half
                    int col = n0 + half * 32 + colL;
                    float bv = bias[col];
                    #pragma unroll
                    for (int i = 0; i < 2; i++) {
                        int rowL = wm * 32 + i * 16 + quad * 4;
                        float v4[4];
                        #pragma unroll
                        for (int r = 0; r < 4; r++) {
                            int rr = m0 + rowL + r; if (rr > M - 1) rr = M - 1;
                            v4[r] = acc[i][j][r] + bv + resid[(size_t)rr * N + col];
                        }
                        float4 pk = { v4[0], v4[1], v4[2], v4[3] };
                        *(float4*)&Tt[colL * 68 + rowL] = pk;
                    }
                }
            }
            __syncthreads();
            int c = tid >> 3, no = (tid & 7) * 8;
            int col = n0 + half * 32 + c;
            #pragma unroll
            for (int q2 = 0; q2 < 2; q2++) {
                int nn = no + q2 * 4;
                int row = m0 + nn;
                if (row >= M) continue;
                int b2 = row / NTOK, n2 = row - b2 * NTOK;
                float4 v = *(float4*)&Tt[c * 68 + nn];
                *(float4*)((float*)out + ((size_t)(b2 * N + col)) * NTOK + n2) = v;
            }
        }
        return;
    }

    #pragma unroll
    for (int j = 0; j < 2; j++) {
        int col = n0 + wn * 32 + j * 16 + l16;
        float bv = bias ? bias[col] : 0.f;
        #pragma unroll
        for (int i = 0; i < 2; i++) {
            int row0 = m0 + wm * 32 + i * 16 + quad * 4;
            if (row0 >= M) continue;
            #pragma unroll
            for (int r = 0; r < 4; r++) {
                float v = acc[i][j][r] + bv;
                if (flags & F_RESID) v += resid[(size_t)(row0 + r) * N + col];
                ((float*)out)[(size_t)(row0 + r) * N + col] = v;
            }
        }
    }
}
__global__ __launch_bounds__(256) void k_fc2(const __bf16* A, const __bf16* B,
        const float* bias, const float* resid, void* out, int M, int N, int K) {
    gemm64_body(A, B, bias, resid, out, M, N, K, F_RESID | F_TRANS);
}

// ---------------------------------------------------------------------------
// k_attn R23 = best config + l-sum offloaded to MFMA: with swapped-QK the
// softmax denominator is a column-sum of P, computed exactly by
// mfma(ones, pb, lacc) (A=all-ones -> D[r][q] = sum_k P[k][q]; every lane
// gets its query's full tile sum, OOB keys already zeroed in pb). Replaces
// 16 VALU adds/tile + 2 end shuffles with 2 MFMA/tile on the 18%-idle MFMA
// pipe (VALU was the busiest pipe at 52%). Denominator now sums the same
// bf16-rounded P the PV numerator uses (consistent numerics).
// Zero-LDS softmax, 8 waves x 16 q, KSPLIT=4, grid 1056, VT2 b128 PV,
// wave-linear OP stores, XCD grouping.
// ---------------------------------------------------------------------------
__global__ __launch_bounds__(512, 8) void k_attn(const __bf16* __restrict__ qkv,
                                                 const __bf16* __restrict__ vt,
                                                 __bf16* __restrict__ opart,
                                                 float* __restrict__ lpart) {
    __shared__ __align__(16) __bf16 KV[2][2][64][64];   // 32 KB: [buf][K/V][row][col]
    __bf16 (*Qs)[64] = (__bf16(*)[64])KV;               // 16 KB overlay (= buf0)

    int tid = threadIdx.x, lane = tid & 63, wid = tid >> 6;
    int quad = lane >> 4, l16 = lane & 15;
    // XCD-aware remap: flat%8 = XCD (round-robin dispatch); same (bh,ks) -> one XCD
    int flat = blockIdx.x;
    int xcd = flat & 7, slot = flat >> 3;     // slot 0..131
    int grp = slot / NQB, qb = slot - grp * NQB;
    int g = xcd + 8 * grp;                    // 0..47
    int bh = g % 12, ks = g / 12;
    int q0 = qb * 128;
    int b = bh / HEADS, h = bh % HEADS;
    int x7 = l16 & 7;

    int kt0 = (43 * ks) / KSPLIT, kt1 = (43 * (ks + 1)) / KSPLIT;

    // per-thread staging geometry: one gll16 each for K and V per tile
    int srow = tid >> 3, scc = (tid & 7) ^ (srow & 7);
    const __bf16* pK = qkv + ((size_t)(b * NTOK + kt0 * 64 + srow)) * 1152 + 384 + h * 64 + scc * 8;
    const __bf16* pV = vt + ((size_t)(bh * 64 + srow)) * NTOKP + kt0 * 64 + scc * 8;

    auto stageKV = [&](int kt, int bufi) {
        const __bf16* kp = pK + (size_t)(kt - kt0) * (64 * 1152);
        if (kt == 42 && srow >= 56)   // clamp tail rows (keys >= NTOK)
            kp = qkv + ((size_t)(b * NTOK + NTOK - 1)) * 1152 + 384 + h * 64 + scc * 8;
        gll16(kp, &KV[bufi][0][0][0] + (size_t)tid * 8);
        gll16(pV + (size_t)(kt - kt0) * 64, &KV[bufi][1][0][0] + (size_t)tid * 8);
    };

    // ---- prologue: stage Q (128 rows = 1024 granules) into the buf0 overlay ----
    #pragma unroll
    for (int i = 0; i < 2; i++) {
        int c = i * 512 + tid;
        int row = c >> 3, cc = (c & 7) ^ (row & 7);
        int gq = q0 + row; if (gq > NTOK - 1) gq = NTOK - 1;
        gll16(qkv + ((size_t)(b * NTOK + gq)) * 1152 + h * 64 + cc * 8,
              &Qs[0][0] + (size_t)c * 8);
    }
    __syncthreads();   // Q staged

    bf16x8 aq[2];
    #pragma unroll
    for (int sx = 0; sx < 2; sx++)
        aq[sx] = *(bf16x8*)&Qs[wid * 16 + l16][((sx * 4 + quad) ^ x7) * 8];
    __syncthreads();   // all waves done reading Qs before buf0 overwrite

    stageKV(kt0, 0);

    // lane-constant LDS read offsets (elements)
    int koff0 = (quad ^ x7) * 8, koff1 = ((4 + quad) ^ x7) * 8;
    int voff0 = ((quad * 2 + 0) ^ x7) * 8, voff1 = ((quad * 2 + 1) ^ x7) * 8;

    const f32x4 fzero = {0.f, 0.f, 0.f, 0.f};
    const __bf16 one = (__bf16)1.f;
    const bf16x8 aones = { one, one, one, one, one, one, one, one };
    f32x4 oaccT[4] = {};   // O^T: row d = dt*16+quad*4+r, col q = l16
    f32x4 lacc = {0.f, 0.f, 0.f, 0.f};   // l per query q=l16 (all rows equal)

    int bufi = 0;
    for (int kt = kt0; kt < kt1; kt++) {
        __syncthreads();                          // stage(kt) landed; prev readers done
        if (kt + 1 < kt1) stageKV(kt + 1, bufi ^ 1);   // prefetch next tile

        const __bf16* ksb = &KV[bufi][0][0][0] + l16 * 64;
        const __bf16* vtb = &KV[bufi][1][0][0] + l16 * 64;
        bool tail = (kt == 42);

        // S^T per 16-key block t; exp in-register -> pb B-fragments (no LDS)
        bf16x8 pb[2];
        #pragma unroll
        for (int t = 0; t < 4; t++) {
            bf16x8 bk0 = *(bf16x8*)(ksb + t * 1024 + koff0);
            bf16x8 bk1 = *(bf16x8*)(ksb + t * 1024 + koff1);
            __builtin_amdgcn_s_setprio(1);
            f32x4 z = __builtin_amdgcn_mfma_f32_16x16x32_bf16(bk0, aq[0], fzero, 0, 0, 0);
            z = __builtin_amdgcn_mfma_f32_16x16x32_bf16(bk1, aq[1], z, 0, 0, 0);
            __builtin_amdgcn_s_setprio(0);
            float e0 = exp2f(z[0]), e1 = exp2f(z[1]), e2 = exp2f(z[2]), e3 = exp2f(z[3]);
            if (tail) {
                int kb = kt * 64 + t * 16 + quad * 4;
                if (kb + 0 >= NTOK) e0 = 0.f;
                if (kb + 1 >= NTOK) e1 = 0.f;
                if (kb + 2 >= NTOK) e2 = 0.f;
                if (kb + 3 >= NTOK) e3 = 0.f;
            }
            int half = (t & 1) * 4, px = t >> 1;
            pb[px][half + 0] = (__bf16)e0;
            pb[px][half + 1] = (__bf16)e1;
            pb[px][half + 2] = (__bf16)e2;
            pb[px][half + 3] = (__bf16)e3;
        }

        // PV + l: per (dt,sx) ONE contiguous b128 V^T fragment, 2 MFMA;
        // l column-sum via 2 ones-MFMA (replaces 16 VALU adds + end shuffles)
        __builtin_amdgcn_s_setprio(1);
        lacc = __builtin_amdgcn_mfma_f32_16x16x32_bf16(aones, pb[0], lacc, 0, 0, 0);
        lacc = __builtin_amdgcn_mfma_f32_16x16x32_bf16(aones, pb[1], lacc, 0, 0, 0);
        #pragma unroll
        for (int dt = 0; dt < 4; dt++) {
            const __bf16* vr = vtb + dt * 1024;
            bf16x8 av0 = *(bf16x8*)(vr + voff0);
            bf16x8 av1 = *(bf16x8*)(vr + voff1);
            oaccT[dt] = __builtin_amdgcn_mfma_f32_16x16x32_bf16(av0, pb[0], oaccT[dt], 0, 0, 0);
            oaccT[dt] = __builtin_amdgcn_mfma_f32_16x16x32_bf16(av1, pb[1], oaccT[dt], 0, 0, 0);
        }
        __builtin_amdgcn_s_setprio(0);
        bufi ^= 1;
    }

    // softmax denominator: lacc[0] already holds the full per-query sum
    int gq = q0 + wid * 16 + l16;
    if (quad == 0 && gq < NTOK)
        lpart[((size_t)ks * 12 + bh) * NTOK + gq] = lacc[0];

    // store unnormalized partials: wave-linear OP layout, 512 B per store
    __bf16* op = opart + ((((size_t)(ks * 12 + bh) * NQB + qb) * 8 + wid) * 1024);
    #pragma unroll
    for (int dt = 0; dt < 4; dt++) {
        bf16x4 pk = { (__bf16)oaccT[dt][0], (__bf16)oaccT[dt][1],
                      (__bf16)oaccT[dt][2], (__bf16)oaccT[dt][3] };
        *(bf16x4*)(op + (dt * 64 + lane) * 4) = pk;
    }
}

// ---------------------------------------------------------------------------
// k_comb: combine split-K partials (wave-linear OP layout) -> O bf16.
// ---------------------------------------------------------------------------
__global__ void k_comb(const __bf16* __restrict__ opart,
                       const float* __restrict__ lpart,
                       __bf16* __restrict__ o) {
    int idx = blockIdx.x * 256 + threadIdx.x;   // MTOT*96 total
    int token = idx / 96, rem = idx - token * 96;
    int c = rem * 4, h = c >> 6;
    int b2 = token / NTOK, n = token - b2 * NTOK;
    int bh = b2 * HEADS + h;
    // decode wave-linear OP coordinates (128 q/block, 16 q/wave)
    int qb = n >> 7, nb = n & 127;
    int wid = nb >> 4, l16 = nb & 15;
    int ch = c & 63, dt = ch >> 4, quad = (ch >> 2) & 3;
    int lane = quad * 16 + l16;
    size_t gbase = (((size_t)bh * NQB + qb) * 8 + wid) * 1024 + (dt * 64 + lane) * 4;
    const size_t kstride = (size_t)12 * NQB * 8 * 1024;   // elems per ks slice
    float a0 = 0.f, a1 = 0.f, a2 = 0.f, a3 = 0.f, l = 0.f;
    #pragma unroll
    for (int ks = 0; ks < KSPLIT; ks++) {
        bf16x4 p = *(const bf16x4*)&opart[(size_t)ks * kstride + gbase];
        a0 += (float)p[0]; a1 += (float)p[1]; a2 += (float)p[2]; a3 += (float)p[3];
        l += lpart[((size_t)ks * 12 + bh) * NTOK + n];
    }
    float inv = 1.f / l;
    bf16x4 ov = { (__bf16)(a0 * inv), (__bf16)(a1 * inv),
                  (__bf16)(a2 * inv), (__bf16)(a3 * inv) };
    *(bf16x4*)(o + (size_t)token * DIM + c) = ov;
}

// ---------------------------------------------------------------------------
extern "C" void kernel_launch(void* const* d_in, const int* in_sizes, int n_in,
                              void* d_out, int out_size, void* d_ws, size_t ws_size,
                              hipStream_t stream) {
    const float* x      = (const float*)d_in[0];
    const float* conv_w = (const float*)d_in[1];
    // d_in[2] conv_b cancels in reference
    const float* ln1_w  = (const float*)d_in[3];
    const float* ln1_b  = (const float*)d_in[4];
    const float* qkv_w  = (const float*)d_in[5];
    const float* proj_w = (const float*)d_in[6];
    const float* proj_b = (const float*)d_in[7];
    const float* ln2_w  = (const float*)d_in[8];
    const float* ln2_b  = (const float*)d_in[9];
    const float* fc1_w  = (const float*)d_in[10];
    const float* fc1_b  = (const float*)d_in[11];
    const float* fc2_w  = (const float*)d_in[12];
    const float* fc2_b  = (const float*)d_in[13];
    float* out = (float*)d_out;

    char* p = (char*)d_ws;
    float*  T    = (float*)p;  p += (size_t)MTOT * DIM * 4;           //  8.4 MB
    __bf16* TN   = (__bf16*)p; p += (size_t)MTOT * DIM * 2;           //  4.2 MB
    __bf16* QKV  = (__bf16*)p; p += (size_t)MTOT * 1152 * 2;          // 12.6 MB
    __bf16* VT   = (__bf16*)p; p += (size_t)BATCH * DIM * NTOKP * 2;  //  4.2 MB
    __bf16* O    = (__bf16*)p; p += (size_t)MTOT * DIM * 2;           //  4.2 MB
    __bf16* H    = (__bf16*)p; p += (size_t)MTOT * HIDDEN * 2;        // 16.9 MB
    __bf16* WQ   = (__bf16*)p; p += (size_t)1152 * 384 * 2;
    __bf16* WP   = (__bf16*)p; p += (size_t)384 * 384 * 2;
    __bf16* W1   = (__bf16*)p; p += (size_t)1536 * 384 * 2;
    __bf16* W2   = (__bf16*)p; p += (size_t)384 * 1536 * 2;
    float*  LP   = (float*)p;  p += (size_t)KSPLIT * 12 * NTOK * 4;   //  0.5 MB
    __bf16* OP   = (__bf16*)p; p += (size_t)KSPLIT * 12 * NQB * 8 * 1024 * 2; // 17.3 MB

    // 1. conv positional embedding + residual + weight cvt + VT pad zero
    k_conv<<<528 + 1728 + 1, 256, 0, stream>>>(
        x, conv_w, T, qkv_w, proj_w, fc1_w, fc2_w, WQ, WP, W1, W2, VT);
    // 2. LN1 -> bf16
    k_ln1<<<MTOT / 4, 256, 0, stream>>>(T, TN, ln1_w, ln1_b);
    // 3. QKV gemm (single-buffer): Q pre-scaled; V -> VT2
    k_qkv<<<dim3(18, 43), 256, 0, stream>>>(TN, WQ, QKV, VT, MTOT, 1152, 384);
    // 4. attention split-K partials (zero-LDS softmax, l via ones-MFMA)
    k_attn<<<NQB * 12 * KSPLIT, 512, 0, stream>>>(QKV, VT, OP, LP);
    k_comb<<<(MTOT * 96) / 256, 256, 0, stream>>>(OP, LP, O);
    // 5. T += O @ proj_w^T + proj_b (128x64 tile)
    k_proj<<<dim3(6, 43), 256, 0, stream>>>(O, WP, proj_b, T, T, MTOT, 384, 384);
    // 6. LN2 -> bf16
    k_ln2<<<MTOT / 4, 256, 0, stream>>>(T, TN, ln2_w, ln2_b);
    // 7. H = gelu(TN @ fc1_w^T + fc1_b) bf16 (single-buffer)
    k_fc1<<<dim3(24, 43), 256, 0, stream>>>(TN, W1, fc1_b, H, MTOT, 1536, 384);
    // 8. out[b,c,n] = T + H @ fc2_w^T + fc2_b (LDS-transposed coalesced store)
    k_fc2<<<dim3(6, 86), 256, 0, stream>>>(H, W2, fc2_b, T, out, MTOT, 384, 1536);
}